// Round 3
// baseline (301.363 us; speedup 1.0000x reference)
//
#include <hip/hip_runtime.h>

#define HW 128
#define KTAPS 255
#define DIMC 256

typedef short short8 __attribute__((ext_vector_type(8)));
typedef float f32x16 __attribute__((ext_vector_type(16)));
typedef unsigned int uint4v __attribute__((ext_vector_type(4)));

__device__ __forceinline__ short f2bf(float f) {
    return __builtin_bit_cast(short, (__bf16)f);
}
__device__ __forceinline__ unsigned int pkbf(float a, float b) {
    unsigned int lo = (unsigned short)__builtin_bit_cast(unsigned short, (__bf16)a);
    unsigned int hi = (unsigned short)__builtin_bit_cast(unsigned short, (__bf16)b);
    return lo | (hi << 16);
}
// 16B-chunk pad: +1 slot every 8 chunks (breaks power-of-2 bank strides)
__device__ __forceinline__ int pad16(int c) { return c + (c >> 3); }

// ---------------- prep: weight fragments per channel -> ws ----------------
// WF1[c] = A_h^T as B-frags (k=r, n=h): val(k,n) = wh[127 + k - n]
// WF2[c] = B_w   as B-frags (k=s, n=w): val(k,n) = ww[127 + k - n]
// B-frag chunk = ((n>>5)*8 + (k>>4))*64 + (n&31) + 32*((k>>3)&1), elem j = k&7
__global__ void build_wfrags(const float* __restrict__ wh,
                             const float* __restrict__ ww,
                             short8* __restrict__ wf) {
    const int c   = blockIdx.x;
    const int tid = threadIdx.x;
    const float* __restrict__ whc = wh + c * KTAPS;
    const float* __restrict__ wwc = ww + c * KTAPS;
    short8* __restrict__ w1 = wf + (size_t)c * 2048;
    short8* __restrict__ w2 = wf + (size_t)(DIMC + c) * 2048;
#pragma unroll
    for (int i = 0; i < 8; ++i) {
        const int ch = tid + (i << 8);          // chunk 0..2047
        const int ln = ch & 63;
        const int ks = (ch >> 6) & 7;
        const int nb = ch >> 9;
        const int n  = (nb << 5) + (ln & 31);
        const int kb = (ks << 4) + ((ln >> 5) << 3);
        const float* p1 = whc + (127 + kb - n); // in [0, 247]
        const float* p2 = wwc + (127 + kb - n);
        short8 v1, v2;
#pragma unroll
        for (int j = 0; j < 8; ++j) { v1[j] = f2bf(p1[j]); v2[j] = f2bf(p2[j]); }
        w1[ch] = v1;
        w2[ch] = v2;
    }
}

// ---------------- main: per (n,c) image ----------------
// mm1: Y^T = X^T * A_h^T  (A = X^T frags from LDS w/ sigma-permuted M, B = WF1 global)
// cvt:  C/D regs land directly in mm2 A-frag layout (sigma cancels) -> registers only
// mm2: Z = Y * B_w        (A = regs, B = WF2 global), epilogue scalar coalesced stores
__global__ __launch_bounds__(256, 3)
void sep_conv255_mfma2(const float* __restrict__ x,
                       const float* __restrict__ bh,
                       const float* __restrict__ bw,
                       const short8* __restrict__ wf,
                       float* __restrict__ out) {
    __shared__ __align__(16) short8 XF[2304];   // 36 KB padded X^T A-frags

    const int blk  = blockIdx.x;                // n*DIMC + c
    const int c    = blk & (DIMC - 1);
    const int tid  = threadIdx.x;
    const int lane = tid & 63;
    const int wv   = tid >> 6;                  // wave id: h-block for mm1 n / mm2 m

    const float* __restrict__ xc = x + (size_t)blk * (HW * HW);
    float* __restrict__ zc       = out + (size_t)blk * (HW * HW);
    const short8* __restrict__ w1 = wf + (size_t)c * 2048;
    const short8* __restrict__ w2 = wf + (size_t)(DIMC + c) * 2048;

    // ---- stage X^T A-frags into LDS, M-index sigma-permuted (swap bits 2,3) ----
    {
        const int s    = tid & 127;             // X column owned by this thread
        const int mp   = (s & ~12) | ((s & 4) << 1) | ((s & 8) >> 1);  // sigma(s)
        const int half = tid >> 7;
#pragma unroll
        for (int i = 0; i < 8; ++i) {
            const int rg = half + (i << 1);     // 8-row group 0..15
            const int r0 = rg << 3;
            float xv[8];
#pragma unroll
            for (int j = 0; j < 8; ++j) xv[j] = xc[(r0 + j) * HW + s];
            uint4v d;
#pragma unroll
            for (int q = 0; q < 4; ++q) d[q] = pkbf(xv[2 * q], xv[2 * q + 1]);
            const int chunk = ((mp >> 5) * 8 + (rg >> 1)) * 64 + (mp & 31) + ((rg & 1) << 5);
            XF[pad16(chunk)] = __builtin_bit_cast(short8, d);
        }
    }

    // ---- preload mm1 B-frags (weights, global, L2-hot) before the barrier ----
    short8 b1[8];
#pragma unroll
    for (int ks = 0; ks < 8; ++ks) b1[ks] = w1[((wv << 3) + ks) * 64 + lane];
    const float bhv = bh[c];
    const float bwv = bw[c];

    __syncthreads();

    // ---- mm1: 4 s-blocks x 8 k-chunks ----
    f32x16 acc1[4];
#pragma unroll
    for (int t = 0; t < 4; ++t)
#pragma unroll
        for (int j = 0; j < 16; ++j) acc1[t][j] = 0.0f;

#pragma unroll
    for (int ks = 0; ks < 8; ++ks) {
#pragma unroll
        for (int mb = 0; mb < 4; ++mb) {
            const short8 a = XF[pad16(((mb << 3) + ks) * 64 + lane)];
            acc1[mb] = __builtin_amdgcn_mfma_f32_32x32x16_bf16(a, b1[ks], acc1[mb], 0, 0, 0);
        }
    }

    // ---- cvt: Y(+bh) -> mm2 A-frags, pure registers (sigma makes this identity) ----
    short8 a2[8];
#pragma unroll
    for (int mb = 0; mb < 4; ++mb) {
        unsigned int d[8];
#pragma unroll
        for (int i = 0; i < 8; ++i)
            d[i] = pkbf(acc1[mb][2 * i] + bhv, acc1[mb][2 * i + 1] + bhv);
        uint4v lo, hi;
#pragma unroll
        for (int q = 0; q < 4; ++q) { lo[q] = d[q]; hi[q] = d[4 + q]; }
        a2[2 * mb]     = __builtin_bit_cast(short8, lo);
        a2[2 * mb + 1] = __builtin_bit_cast(short8, hi);
    }

    // ---- mm2 + fused epilogue, one 32x32 tile at a time ----
    const int hb = (wv << 5) + ((lane >> 5) << 2);
    const int wl = lane & 31;
#pragma unroll
    for (int t = 0; t < 4; ++t) {
        short8 b2[8];
#pragma unroll
        for (int ks = 0; ks < 8; ++ks) b2[ks] = w2[((t << 3) + ks) * 64 + lane];
        f32x16 acc2;
#pragma unroll
        for (int j = 0; j < 16; ++j) acc2[j] = 0.0f;
#pragma unroll
        for (int ks = 0; ks < 8; ++ks)
            acc2 = __builtin_amdgcn_mfma_f32_32x32x16_bf16(a2[ks], b2[ks], acc2, 0, 0, 0);

        float* __restrict__ zp = zc + (t << 5) + wl;
#pragma unroll
        for (int r = 0; r < 16; ++r) {
            const int h = hb + (r & 3) + ((r >> 2) << 3);
            zp[h * HW] = acc2[r] + bwv;
        }
    }
}

extern "C" void kernel_launch(void* const* d_in, const int* in_sizes, int n_in,
                              void* d_out, int out_size, void* d_ws, size_t ws_size,
                              hipStream_t stream) {
    const float* x  = (const float*)d_in[0];
    const float* wh = (const float*)d_in[1];
    const float* bh = (const float*)d_in[2];
    const float* ww = (const float*)d_in[3];
    const float* bw = (const float*)d_in[4];
    float* outp = (float*)d_out;
    short8* wf = (short8*)d_ws;   // needs 2*256*2048*16 B = 16 MB scratch

    const int nbatch = in_sizes[0] / (DIMC * HW * HW);  // = 10

    hipLaunchKernelGGL(build_wfrags, dim3(DIMC), dim3(256), 0, stream, wh, ww, wf);
    hipLaunchKernelGGL(sep_conv255_mfma2, dim3(nbatch * DIMC), dim3(256), 0, stream,
                       x, bh, bw, wf, outp);
}